// Round 1
// baseline (671.615 us; speedup 1.0000x reference)
//
#include <hip/hip_runtime.h>
#include <hip/hip_bf16.h>

#define HH 56
#define WW 56
#define HW 3136           // 56*56
#define CIN 256
#define COUT 512
#define NBATCH 32
#define EPS 1e-5f
#define DW_TH 4.0f
#define PW_TH 1e-3f

// ---------------- Kernel 1: depthwise 3x3 + bias + BN1 + ReLU + channel cut ----------------
// one block per (n, c) plane; plane staged in LDS; block-wide max; conditional write
__global__ __launch_bounds__(256) void dw_kernel(
    const float* __restrict__ x, const float* __restrict__ dw_w,
    const float* __restrict__ dw_b,
    const float* __restrict__ g1, const float* __restrict__ b1,
    const float* __restrict__ m1, const float* __restrict__ v1,
    float* __restrict__ y)
{
    __shared__ float xs[HW];
    __shared__ float ys[HW];
    __shared__ float redbuf[4];

    const int b = blockIdx.x;
    const int n = b >> 8;          // /256
    const int c = b & 255;
    const int t = threadIdx.x;

    const float* xp = x + (size_t)(n * CIN + c) * HW;

    for (int p = t; p < HW; p += 256) xs[p] = xp[p];

    float wv[9];
    const float* wp = dw_w + c * 9;
#pragma unroll
    for (int i = 0; i < 9; ++i) wv[i] = wp[i];
    const float bias = dw_b[c];
    const float sc = g1[c] * rsqrtf(v1[c] + EPS);
    const float sh = b1[c] - m1[c] * sc;

    __syncthreads();

    float lmax = 0.0f;
    for (int p = t; p < HW; p += 256) {
        const int hh = p / WW;
        const int ww = p - hh * WW;
        float s = 0.0f;
#pragma unroll
        for (int dy = -1; dy <= 1; ++dy) {
            const int yy = hh + dy;
            if ((unsigned)yy < (unsigned)HH) {
#pragma unroll
                for (int dx = -1; dx <= 1; ++dx) {
                    const int xx = ww + dx;
                    if ((unsigned)xx < (unsigned)WW)
                        s = fmaf(wv[(dy + 1) * 3 + (dx + 1)], xs[yy * WW + xx], s);
                }
            }
        }
        float v = fmaxf(fmaf(s + bias, sc, sh), 0.0f);  // bn then relu; v >= 0 so |v| = v
        ys[p] = v;
        lmax = fmaxf(lmax, v);
    }

    // wave (64-lane) reduce then cross-wave via LDS
#pragma unroll
    for (int off = 32; off > 0; off >>= 1)
        lmax = fmaxf(lmax, __shfl_down(lmax, off));
    const int lane = t & 63, wid = t >> 6;
    if (lane == 0) redbuf[wid] = lmax;
    __syncthreads();
    const float bmax = fmaxf(fmaxf(redbuf[0], redbuf[1]), fmaxf(redbuf[2], redbuf[3]));

    float* yp = y + (size_t)(n * CIN + c) * HW;
    if (bmax < DW_TH) {
        for (int p = t; p < HW; p += 256) yp[p] = 0.0f;
    } else {
        for (int p = t; p < HW; p += 256) yp[p] = ys[p];
    }
}

// ---------------- Kernel 2: pointwise 1x1 (GEMM) + bias + BN2 + ReLU + per-plane max ----------------
// grid: (49 hw-tiles, 8 o-tiles, 32 n); block 256 threads; tile 64(O) x 64(HW) x 16(K)
__global__ __launch_bounds__(256) void pw_kernel(
    const float* __restrict__ y, const float* __restrict__ pw_w,
    const float* __restrict__ pw_b,
    const float* __restrict__ g2, const float* __restrict__ b2,
    const float* __restrict__ m2, const float* __restrict__ v2,
    float* __restrict__ out, unsigned int* __restrict__ omax)
{
    __shared__ float wt[16][68];   // [kk][o], padded row (68*4B: 16B-aligned cols, no 32-stride)
    __shared__ float yt[16][64];   // [kk][hw]
    __shared__ unsigned int lmax[64];

    const int hw0 = blockIdx.x * 64;
    const int o0  = blockIdx.y * 64;
    const int n   = blockIdx.z;
    const int t   = threadIdx.x;
    const int tx  = t & 15;        // hw micro index
    const int ty  = t >> 4;        // o micro index

    float acc[4][4] = {{0.f}};

    for (int k0 = 0; k0 < CIN; k0 += 16) {
        {   // load W tile: w[o0+i][k0+kk], transposed into wt[kk][i]
            const int i = t >> 2;
            const int kk4 = (t & 3) * 4;
            const float4 wv4 = *(const float4*)(pw_w + (size_t)(o0 + i) * CIN + k0 + kk4);
            wt[kk4 + 0][i] = wv4.x;
            wt[kk4 + 1][i] = wv4.y;
            wt[kk4 + 2][i] = wv4.z;
            wt[kk4 + 3][i] = wv4.w;
        }
        {   // load Y tile: y[n][k0+kk][hw0 + j]
            const int kk = t >> 4;
            const int j4 = (t & 15) * 4;
            const float4 yv4 = *(const float4*)(y + ((size_t)(n * CIN + k0 + kk)) * HW + hw0 + j4);
            *(float4*)&yt[kk][j4] = yv4;
        }
        __syncthreads();
#pragma unroll
        for (int kk = 0; kk < 16; ++kk) {
            const float4 wr = *(const float4*)&wt[kk][ty * 4];
            const float4 yr = *(const float4*)&yt[kk][tx * 4];
            const float wa[4] = {wr.x, wr.y, wr.z, wr.w};
            const float ya[4] = {yr.x, yr.y, yr.z, yr.w};
#pragma unroll
            for (int i = 0; i < 4; ++i)
#pragma unroll
                for (int j = 0; j < 4; ++j)
                    acc[i][j] = fmaf(wa[i], ya[j], acc[i][j]);
        }
        __syncthreads();
    }

    if (t < 64) lmax[t] = 0u;
    __syncthreads();

#pragma unroll
    for (int i = 0; i < 4; ++i) {
        const int o = o0 + ty * 4 + i;
        const float sc = g2[o] * rsqrtf(v2[o] + EPS);
        const float sh = (b2[o] - m2[o] * sc) + pw_b[o] * sc;
        float vals[4];
        float rowmax = 0.0f;
#pragma unroll
        for (int j = 0; j < 4; ++j) {
            const float v = fmaxf(fmaf(acc[i][j], sc, sh), 0.0f);
            vals[j] = v;
            rowmax = fmaxf(rowmax, v);
        }
        float4 res = make_float4(vals[0], vals[1], vals[2], vals[3]);
        *(float4*)(out + ((size_t)(n * COUT + o)) * HW + hw0 + tx * 4) = res;
        atomicMax(&lmax[ty * 4 + i], __float_as_uint(rowmax));  // v>=0: uint order == float order
    }
    __syncthreads();
    if (t < 64) atomicMax(&omax[n * COUT + o0 + t], lmax[t]);
}

// ---------------- Kernel 3: apply pointwise channel cut ----------------
__global__ __launch_bounds__(256) void cut_kernel(
    const unsigned int* __restrict__ omax, float* __restrict__ out)
{
    const int b = blockIdx.x;   // n*COUT + o
    const float m = __uint_as_float(omax[b]);
    if (m >= PW_TH) return;     // keep: reference zeros only when max < th
    float* p = out + (size_t)b * HW;
    for (int i = threadIdx.x; i < HW; i += 256) p[i] = 0.0f;
}

extern "C" void kernel_launch(void* const* d_in, const int* in_sizes, int n_in,
                              void* d_out, int out_size, void* d_ws, size_t ws_size,
                              hipStream_t stream) {
    const float* x   = (const float*)d_in[0];
    const float* dww = (const float*)d_in[1];
    const float* dwb = (const float*)d_in[2];
    const float* g1  = (const float*)d_in[3];
    const float* b1  = (const float*)d_in[4];
    const float* m1  = (const float*)d_in[5];
    const float* v1  = (const float*)d_in[6];
    const float* pww = (const float*)d_in[7];
    const float* pwb = (const float*)d_in[8];
    const float* g2  = (const float*)d_in[9];
    const float* b2  = (const float*)d_in[10];
    const float* m2  = (const float*)d_in[11];
    const float* v2  = (const float*)d_in[12];
    float* out = (float*)d_out;

    // workspace layout: [0, 64KB): per-(n,o) max (16384 u32); [64KB, ...): y intermediate
    unsigned int* omax = (unsigned int*)d_ws;
    float* y = (float*)((char*)d_ws + 65536);

    hipMemsetAsync(omax, 0, NBATCH * COUT * sizeof(unsigned int), stream);

    dw_kernel<<<NBATCH * CIN, 256, 0, stream>>>(x, dww, dwb, g1, b1, m1, v1, y);

    dim3 g2d(HW / 64, COUT / 64, NBATCH);   // 49, 8, 32
    pw_kernel<<<g2d, 256, 0, stream>>>(y, pww, pwb, g2, b2, m2, v2, out, omax);

    cut_kernel<<<NBATCH * COUT, 256, 0, stream>>>(omax, out);
}

// Round 2
// 493.075 us; speedup vs baseline: 1.3621x; 1.3621x over previous
//
#include <hip/hip_runtime.h>
#include <hip/hip_bf16.h>

#define HH 56
#define WW 56
#define HW 3136
#define CIN 256
#define COUT 512
#define NBATCH 32
#define EPS 1e-5f
#define DW_TH 4.0f
#define PW_TH 1e-3f

typedef __attribute__((ext_vector_type(8))) short s16x8;
typedef __attribute__((ext_vector_type(4))) float f32x4;
typedef unsigned int u32;
typedef unsigned short u16;

__device__ __forceinline__ void async_copy16(void* lds, const void* g) {
    __builtin_amdgcn_global_load_lds((const __attribute__((address_space(1))) unsigned int*)g,
                                     (__attribute__((address_space(3))) unsigned int*)lds,
                                     16, 0, 0);
}

__device__ __forceinline__ u16 bf16_bits(float f) {
    __hip_bfloat16 h = __float2bfloat16(f);
    union { __hip_bfloat16 h; u16 u; } cv; cv.h = h; return cv.u;
}

// ---------------- prep: W fp32 -> bf16, fold BN2+bias into per-o (scale, shift) ----------------
__global__ __launch_bounds__(256) void prep_kernel(
    const float* __restrict__ pww, const float* __restrict__ pwb,
    const float* __restrict__ g2, const float* __restrict__ b2,
    const float* __restrict__ m2, const float* __restrict__ v2,
    u16* __restrict__ wb, float2* __restrict__ scsh)
{
    const int gid = blockIdx.x * 256 + threadIdx.x;     // 16384 threads
    const int base = gid * 8;                           // 131072 elems
    const float4 a = *(const float4*)(pww + base);
    const float4 b = *(const float4*)(pww + base + 4);
    union { u16 u[8]; s16x8 v; } pk;
    pk.u[0] = bf16_bits(a.x); pk.u[1] = bf16_bits(a.y);
    pk.u[2] = bf16_bits(a.z); pk.u[3] = bf16_bits(a.w);
    pk.u[4] = bf16_bits(b.x); pk.u[5] = bf16_bits(b.y);
    pk.u[6] = bf16_bits(b.z); pk.u[7] = bf16_bits(b.w);
    *(s16x8*)(wb + base) = pk.v;
    if (gid < COUT) {
        const float sc = g2[gid] * rsqrtf(v2[gid] + EPS);
        const float sh = fmaf(-m2[gid], sc, b2[gid]) + pwb[gid] * sc;
        scsh[gid] = make_float2(sc, sh);
    }
}

// ---------------- dw: 3x3 depthwise + BN1 + ReLU, write y NHWC bf16, per-(n,c) atomic max ----------------
// grid 1792 = 32 n * 56 rows; block 256 = one thread per channel; XCD-swizzled row assignment
__global__ __launch_bounds__(256) void dw_kernel(
    const float* __restrict__ x, const float* __restrict__ dww, const float* __restrict__ dwb,
    const float* __restrict__ g1, const float* __restrict__ b1,
    const float* __restrict__ m1, const float* __restrict__ v1,
    u16* __restrict__ y, u32* __restrict__ dwmax)
{
    const int bid = blockIdx.x;
    const int x8 = bid & 7;            // XCD-local row group
    const int q  = bid >> 3;           // 0..223
    const int r7 = q % 7;
    const int n  = q / 7;
    const int hh = x8 * 7 + r7;        // rows [7*x8, 7*x8+7) stay on one XCD
    const int c  = threadIdx.x;

    const float* xp = x + (size_t)(n * CIN + c) * HW;
    const float* r0 = xp + hh * WW;
    const float* rm = (hh > 0)      ? r0 - WW : r0;
    const float* rp = (hh < HH - 1) ? r0 + WW : r0;

    const float* wp = dww + c * 9;
    float w00 = wp[0], w01 = wp[1], w02 = wp[2];
    float w10 = wp[3], w11 = wp[4], w12 = wp[5];
    float w20 = wp[6], w21 = wp[7], w22 = wp[8];
    if (hh == 0)      { w00 = w01 = w02 = 0.f; }
    if (hh == HH - 1) { w20 = w21 = w22 = 0.f; }

    const float sc = g1[c] * rsqrtf(v1[c] + EPS);
    const float sh = fmaf(-m1[c], sc, b1[c]) + dwb[c] * sc;   // bias folded

    float4 cm = *(const float4*)rm;
    float4 c0 = *(const float4*)r0;
    float4 cp = *(const float4*)rp;
    float lm = 0.f, l0 = 0.f, lp = 0.f;
    float vmax = 0.f;

    u16* yo = y + (size_t)(n * HW + hh * WW) * CIN + c;

    for (int ch = 0; ch < 14; ++ch) {
        float4 nm, n0, np;
        if (ch < 13) {
            nm = *(const float4*)(rm + 4 * ch + 4);
            n0 = *(const float4*)(r0 + 4 * ch + 4);
            np = *(const float4*)(rp + 4 * ch + 4);
        } else {
            nm = n0 = np = make_float4(0.f, 0.f, 0.f, 0.f);
        }
        float s0 = w00*lm   + w01*cm.x + w02*cm.y
                 + w10*l0   + w11*c0.x + w12*c0.y
                 + w20*lp   + w21*cp.x + w22*cp.y;
        float s1 = w00*cm.x + w01*cm.y + w02*cm.z
                 + w10*c0.x + w11*c0.y + w12*c0.z
                 + w20*cp.x + w21*cp.y + w22*cp.z;
        float s2 = w00*cm.y + w01*cm.z + w02*cm.w
                 + w10*c0.y + w11*c0.z + w12*c0.w
                 + w20*cp.y + w21*cp.z + w22*cp.w;
        float s3 = w00*cm.z + w01*cm.w + w02*nm.x
                 + w10*c0.z + w11*c0.w + w12*n0.x
                 + w20*cp.z + w21*cp.w + w22*np.x;
        const float v0 = fmaxf(fmaf(s0, sc, sh), 0.f);
        const float v1s = fmaxf(fmaf(s1, sc, sh), 0.f);
        const float v2s = fmaxf(fmaf(s2, sc, sh), 0.f);
        const float v3 = fmaxf(fmaf(s3, sc, sh), 0.f);
        vmax = fmaxf(fmaxf(vmax, fmaxf(v0, v1s)), fmaxf(v2s, v3));
        yo[(4 * ch + 0) * CIN] = bf16_bits(v0);
        yo[(4 * ch + 1) * CIN] = bf16_bits(v1s);
        yo[(4 * ch + 2) * CIN] = bf16_bits(v2s);
        yo[(4 * ch + 3) * CIN] = bf16_bits(v3);
        lm = cm.w; l0 = c0.w; lp = cp.w;
        cm = nm; c0 = n0; cp = np;
    }
    atomicMax(&dwmax[n * CIN + c], __float_as_uint(vmax));   // v >= 0: uint order == float order
}

// ---------------- dw channel cut fixup (rare path; exits immediately when kept) ----------------
__global__ __launch_bounds__(64) void dwcut_kernel(const u32* __restrict__ dwmax, u16* __restrict__ y)
{
    const int b = blockIdx.x;          // n*CIN + c
    if (__uint_as_float(dwmax[b]) >= DW_TH) return;
    const int n = b >> 8, c = b & 255;
    for (int hw = threadIdx.x; hw < HW; hw += 64)
        y[(size_t)(n * HW + hw) * CIN + c] = 0;
}

// ---------------- pw: bf16 MFMA GEMM (m97-style) + BN2/bias/ReLU + per-(n,o) atomic max ----------------
// grid (28 hw-tiles, 4 o-tiles, 32 n); block 256 = 4 waves; tile O=128 x HW=112, BK=32
__global__ __launch_bounds__(256) void pw_kernel(
    const u16* __restrict__ y, const u16* __restrict__ wb,
    const float2* __restrict__ scsh,
    float* __restrict__ out, u32* __restrict__ omax)
{
    __shared__ u16 Wt[128 * 32];   // [o][k], pitch 64B
    __shared__ u16 Yt[112 * 32];   // [hw][k], pitch 64B

    const int hwt = blockIdx.x, ot = blockIdx.y, n = blockIdx.z;
    const int t = threadIdx.x;
    const int w = t >> 6;          // wave id 0..3
    const int l = t & 63;
    const int lo = l & 15, hi = l >> 4;

    const int o_blk  = ot * 128;
    const int hw_blk = n * HW + hwt * 112;

    // staging source lanes: 16 rows x 64B per wave-instr
    const u16* wg  = wb + (size_t)(o_blk + w * 32 + (l >> 2)) * CIN + (l & 3) * 8;
    const u16* yg  = y  + (size_t)(hw_blk + (l >> 2)) * CIN + (l & 3) * 8;
    char* WtB = (char*)Wt;
    char* YtB = (char*)Yt;

    f32x4 acc[2][7];
#pragma unroll
    for (int s = 0; s < 2; ++s)
#pragma unroll
        for (int j = 0; j < 7; ++j) acc[s][j] = (f32x4){0.f, 0.f, 0.f, 0.f};

    for (int k0 = 0; k0 < CIN; k0 += 32) {
        // stage W tile: wave w covers o rows [w*32, w*32+32)
        async_copy16(WtB + (w * 32 + 0) * 64, wg + k0);
        async_copy16(WtB + (w * 32 + 16) * 64, wg + k0 + (size_t)16 * CIN);
        // stage Y tile: 7 chunks of 16 rows; wave w does chunks 2w, 2w+1 (skip 7)
        {
            const int j0 = 2 * w;
            async_copy16(YtB + j0 * 16 * 64, yg + k0 + (size_t)(j0 * 16) * CIN);
            if (j0 + 1 < 7)
                async_copy16(YtB + (j0 + 1) * 16 * 64, yg + k0 + (size_t)((j0 + 1) * 16) * CIN);
        }
        __syncthreads();

        s16x8 af[2], bf[7];
#pragma unroll
        for (int s = 0; s < 2; ++s)
            af[s] = *(const s16x8*)(WtB + (w * 32 + s * 16 + lo) * 64 + hi * 16);
#pragma unroll
        for (int j = 0; j < 7; ++j)
            bf[j] = *(const s16x8*)(YtB + (j * 16 + lo) * 64 + hi * 16);
#pragma unroll
        for (int s = 0; s < 2; ++s)
#pragma unroll
            for (int j = 0; j < 7; ++j)
                acc[s][j] = __builtin_amdgcn_mfma_f32_16x16x32_bf16(af[s], bf[j], acc[s][j], 0, 0, 0);
        __syncthreads();
    }

    // epilogue: C/D layout col=lane&15 (hw), row=(lane>>4)*4+reg (o)
#pragma unroll
    for (int s = 0; s < 2; ++s) {
#pragma unroll
        for (int r = 0; r < 4; ++r) {
            const int o = o_blk + w * 32 + s * 16 + hi * 4 + r;
            const float2 ss = scsh[o];
            float m = 0.f;
            float* op = out + (size_t)(n * COUT + o) * HW + hwt * 112 + lo;
#pragma unroll
            for (int j = 0; j < 7; ++j) {
                const float v = fmaxf(fmaf(acc[s][j][r], ss.x, ss.y), 0.f);
                op[j * 16] = v;
                m = fmaxf(m, v);
            }
            m = fmaxf(m, __shfl_xor(m, 1));
            m = fmaxf(m, __shfl_xor(m, 2));
            m = fmaxf(m, __shfl_xor(m, 4));
            m = fmaxf(m, __shfl_xor(m, 8));
            if (lo == 0) atomicMax(&omax[n * COUT + o], __float_as_uint(m));
        }
    }
}

// ---------------- pw channel cut fixup ----------------
__global__ __launch_bounds__(256) void pwcut_kernel(const u32* __restrict__ omax, float* __restrict__ out)
{
    const int b = blockIdx.x;   // n*COUT + o
    if (__uint_as_float(omax[b]) >= PW_TH) return;
    float* p = out + (size_t)b * HW;
    for (int i = threadIdx.x; i < HW; i += 256) p[i] = 0.0f;
}

extern "C" void kernel_launch(void* const* d_in, const int* in_sizes, int n_in,
                              void* d_out, int out_size, void* d_ws, size_t ws_size,
                              hipStream_t stream) {
    const float* x   = (const float*)d_in[0];
    const float* dww = (const float*)d_in[1];
    const float* dwb = (const float*)d_in[2];
    const float* g1  = (const float*)d_in[3];
    const float* b1  = (const float*)d_in[4];
    const float* m1  = (const float*)d_in[5];
    const float* v1  = (const float*)d_in[6];
    const float* pww = (const float*)d_in[7];
    const float* pwb = (const float*)d_in[8];
    const float* g2  = (const float*)d_in[9];
    const float* b2  = (const float*)d_in[10];
    const float* m2  = (const float*)d_in[11];
    const float* v2  = (const float*)d_in[12];
    float* out = (float*)d_out;

    // ws layout: [0,64K) pw omax; [64K,96K) dw max; [96K,100K) scsh; [128K,384K) W bf16; [1M,...) y NHWC bf16
    u32*    omax  = (u32*)d_ws;
    u32*    dwmax = (u32*)((char*)d_ws + (64 << 10));
    float2* scsh  = (float2*)((char*)d_ws + (96 << 10));
    u16*    wbf   = (u16*)((char*)d_ws + (128 << 10));
    u16*    y     = (u16*)((char*)d_ws + (1 << 20));

    hipMemsetAsync(d_ws, 0, 100 << 10, stream);

    prep_kernel<<<64, 256, 0, stream>>>(pww, pwb, g2, b2, m2, v2, wbf, scsh);
    dw_kernel<<<NBATCH * HH, 256, 0, stream>>>(x, dww, dwb, g1, b1, m1, v1, y, dwmax);
    dwcut_kernel<<<NBATCH * CIN, 64, 0, stream>>>(dwmax, y);
    dim3 gpw(HW / 112, COUT / 128, NBATCH);   // 28, 4, 32
    pw_kernel<<<gpw, 256, 0, stream>>>(y, wbf, scsh, out, omax);
    pwcut_kernel<<<NBATCH * COUT, 256, 0, stream>>>(omax, out);
}

// Round 3
// 428.312 us; speedup vs baseline: 1.5681x; 1.1512x over previous
//
#include <hip/hip_runtime.h>
#include <hip/hip_bf16.h>

#define HH 56
#define WW 56
#define HW 3136
#define CIN 256
#define COUT 512
#define NBATCH 32
#define EPS 1e-5f
#define DW_TH 4.0f
#define PW_TH 1e-3f

#define CG 32            // channels per dw block
#define CPITCH 508       // floats per channel in dw LDS (9*56=504 + pad 4; stride 28 mod 32 banks)

typedef __attribute__((ext_vector_type(8))) short s16x8;
typedef __attribute__((ext_vector_type(4))) float f32x4;
typedef unsigned int u32;
typedef unsigned short u16;

__device__ __forceinline__ void async_copy16(void* lds, const void* g) {
    __builtin_amdgcn_global_load_lds((const __attribute__((address_space(1))) unsigned int*)g,
                                     (__attribute__((address_space(3))) unsigned int*)lds,
                                     16, 0, 0);
}

__device__ __forceinline__ u16 bf16_bits(float f) {
    __hip_bfloat16 h = __float2bfloat16(f);
    union { __hip_bfloat16 h; u16 u; } cv; cv.h = h; return cv.u;
}

// ---------------- prep: W fp32 -> bf16, fold BN2+bias into (scale,shift), zero max buffers ----------------
__global__ __launch_bounds__(256) void prep_kernel(
    const float* __restrict__ pww, const float* __restrict__ pwb,
    const float* __restrict__ g2, const float* __restrict__ b2,
    const float* __restrict__ m2, const float* __restrict__ v2,
    u16* __restrict__ wb, float2* __restrict__ scsh,
    u32* __restrict__ omax, u32* __restrict__ dwmax)
{
    const int gid = blockIdx.x * 256 + threadIdx.x;     // 16384 threads
    const int base = gid * 8;                           // covers 131072 = COUT*CIN
    const float4 a = *(const float4*)(pww + base);
    const float4 b = *(const float4*)(pww + base + 4);
    union { u16 u[8]; s16x8 v; } pk;
    pk.u[0] = bf16_bits(a.x); pk.u[1] = bf16_bits(a.y);
    pk.u[2] = bf16_bits(a.z); pk.u[3] = bf16_bits(a.w);
    pk.u[4] = bf16_bits(b.x); pk.u[5] = bf16_bits(b.y);
    pk.u[6] = bf16_bits(b.z); pk.u[7] = bf16_bits(b.w);
    *(s16x8*)(wb + base) = pk.v;
    omax[gid] = 0u;                                     // NBATCH*COUT = 16384
    if (gid < NBATCH * CIN) dwmax[gid] = 0u;            // 8192
    if (gid < COUT) {
        const float sc = g2[gid] * rsqrtf(v2[gid] + EPS);
        const float sh = fmaf(-m2[gid], sc, b2[gid]) + pwb[gid] * sc;
        scsh[gid] = make_float2(sc, sh);
    }
}

// ---------------- dw v2: LDS-staged 3x3 depthwise + BN1 + ReLU -> y NHWC bf16 + per-(n,c) max ----------------
// block = (n, 7-row strip, 32-channel group); 2048 blocks x 256 threads; 63.5 KB LDS
__global__ __launch_bounds__(256) void dw_kernel(
    const float* __restrict__ x, const float* __restrict__ dww, const float* __restrict__ dwb,
    const float* __restrict__ g1, const float* __restrict__ b1,
    const float* __restrict__ m1, const float* __restrict__ v1,
    u16* __restrict__ y, u32* __restrict__ dwmax)
{
    __shared__ float xs[CG * CPITCH];   // [c][local row 0..8][px], rows = strip rows -1..+7

    const int bid = blockIdx.x;
    const int cg = bid & 7;             // channel group (8)
    const int hs = (bid >> 3) & 7;      // strip (8)
    const int n  = bid >> 6;            // batch (32)
    const int t  = threadIdx.x;

    const int g0     = hs * 7 - 1;                 // global row mapped to local slot 0
    const int gstart = (g0 < 0) ? 0 : g0;
    const int gend   = (hs * 7 + 7 > 55) ? 55 : hs * 7 + 7;
    const int nrows  = gend - gstart + 1;          // 8 or 9
    const int dst0   = gstart - g0;                // 1 iff hs==0 else 0
    const int cnt4   = nrows * 14;                 // float4s per channel span

    // zero clipped halo row
    if (hs == 0) {
        for (int i = t; i < CG * 14; i += 256) {
            const int c = i / 14, j = i - c * 14;
            *(float4*)&xs[c * CPITCH + j * 4] = make_float4(0.f, 0.f, 0.f, 0.f);
        }
    } else if (hs == 7) {
        for (int i = t; i < CG * 14; i += 256) {
            const int c = i / 14, j = i - c * 14;
            *(float4*)&xs[c * CPITCH + 8 * 56 + j * 4] = make_float4(0.f, 0.f, 0.f, 0.f);
        }
    }

    // coalesced staging: 2 channels in flight (128 threads each), 16 iterations
    {
        const float* gbase = x + (size_t)(n * CIN + cg * CG) * HW + gstart * 56;
        const int half = t >> 7;
        const int i4 = t & 127;
        for (int cc = 0; cc < 16; ++cc) {
            const int c = cc * 2 + half;
            if (i4 < cnt4) {
                const float4 v = *(const float4*)(gbase + (size_t)c * HW + i4 * 4);
                *(float4*)&xs[c * CPITCH + dst0 * 56 + i4 * 4] = v;
            }
        }
    }
    __syncthreads();

    // compute: thread = (local row r 0..6, channel c 0..31); 224 active
    const int r = t >> 5;
    const int c = t & 31;
    float vmax = 0.f;
    if (r < 7) {
        const int ch = cg * CG + c;
        const float* wp = dww + ch * 9;
        const float w00 = wp[0], w01 = wp[1], w02 = wp[2];
        const float w10 = wp[3], w11 = wp[4], w12 = wp[5];
        const float w20 = wp[6], w21 = wp[7], w22 = wp[8];
        const float sc = g1[ch] * rsqrtf(v1[ch] + EPS);
        const float sh = fmaf(-m1[ch], sc, b1[ch]) + dwb[ch] * sc;

        const float* rm = &xs[c * CPITCH + r * 56];        // global row (hs*7+r)-1
        const float* r0 = rm + 56;
        const float* rp = rm + 112;
        const int grow = hs * 7 + r;
        u16* yo = y + (size_t)(n * HW + grow * WW) * CIN + ch;

        float4 cm = *(const float4*)rm;
        float4 c0 = *(const float4*)r0;
        float4 cp = *(const float4*)rp;
        float lm = 0.f, l0 = 0.f, lp = 0.f;

        for (int chk = 0; chk < 14; ++chk) {
            float4 nm, n0, np;
            if (chk < 13) {
                nm = *(const float4*)(rm + 4 * chk + 4);
                n0 = *(const float4*)(r0 + 4 * chk + 4);
                np = *(const float4*)(rp + 4 * chk + 4);
            } else {
                nm = n0 = np = make_float4(0.f, 0.f, 0.f, 0.f);
            }
            float s0 = w00*lm   + w01*cm.x + w02*cm.y
                     + w10*l0   + w11*c0.x + w12*c0.y
                     + w20*lp   + w21*cp.x + w22*cp.y;
            float s1 = w00*cm.x + w01*cm.y + w02*cm.z
                     + w10*c0.x + w11*c0.y + w12*c0.z
                     + w20*cp.x + w21*cp.y + w22*cp.z;
            float s2 = w00*cm.y + w01*cm.z + w02*cm.w
                     + w10*c0.y + w11*c0.z + w12*c0.w
                     + w20*cp.y + w21*cp.z + w22*cp.w;
            float s3 = w00*cm.z + w01*cm.w + w02*nm.x
                     + w10*c0.z + w11*c0.w + w12*n0.x
                     + w20*cp.z + w21*cp.w + w22*np.x;
            const float v0 = fmaxf(fmaf(s0, sc, sh), 0.f);
            const float v1s = fmaxf(fmaf(s1, sc, sh), 0.f);
            const float v2s = fmaxf(fmaf(s2, sc, sh), 0.f);
            const float v3 = fmaxf(fmaf(s3, sc, sh), 0.f);
            vmax = fmaxf(fmaxf(vmax, fmaxf(v0, v1s)), fmaxf(v2s, v3));
            yo[(4 * chk + 0) * CIN] = bf16_bits(v0);
            yo[(4 * chk + 1) * CIN] = bf16_bits(v1s);
            yo[(4 * chk + 2) * CIN] = bf16_bits(v2s);
            yo[(4 * chk + 3) * CIN] = bf16_bits(v3);
            lm = cm.w; l0 = c0.w; lp = cp.w;
            cm = nm; c0 = n0; cp = np;
        }
    }
    // pair-reduce rows within wave (lanes 32 apart share c), then atomic
    vmax = fmaxf(vmax, __shfl_xor(vmax, 32));
    if ((t & 32) == 0)
        atomicMax(&dwmax[n * CIN + cg * CG + c], __float_as_uint(vmax));
}

// ---------------- dw channel cut fixup (early-exit when kept) ----------------
__global__ __launch_bounds__(64) void dwcut_kernel(const u32* __restrict__ dwmax, u16* __restrict__ y)
{
    const int b = blockIdx.x;          // n*CIN + c
    if (__uint_as_float(dwmax[b]) >= DW_TH) return;
    const int n = b >> 8, c = b & 255;
    for (int hw = threadIdx.x; hw < HW; hw += 64)
        y[(size_t)(n * HW + hw) * CIN + c] = 0;
}

// ---------------- pw: bf16 MFMA GEMM + BN2/bias/ReLU + per-(n,o) max ----------------
// grid (28 hw-tiles, 4 o-tiles, 32 n); block 256 = 4 waves; tile O=128 x HW=112, BK=32
__global__ __launch_bounds__(256) void pw_kernel(
    const u16* __restrict__ y, const u16* __restrict__ wb,
    const float2* __restrict__ scsh,
    float* __restrict__ out, u32* __restrict__ omax)
{
    __shared__ u16 Wt[128 * 32];   // [o][k], pitch 64B
    __shared__ u16 Yt[112 * 32];   // [hw][k], pitch 64B

    const int hwt = blockIdx.x, ot = blockIdx.y, n = blockIdx.z;
    const int t = threadIdx.x;
    const int w = t >> 6;          // wave id 0..3
    const int l = t & 63;
    const int lo = l & 15, hi = l >> 4;

    const int o_blk  = ot * 128;
    const int hw_blk = n * HW + hwt * 112;

    const u16* wg  = wb + (size_t)(o_blk + w * 32 + (l >> 2)) * CIN + (l & 3) * 8;
    const u16* yg  = y  + (size_t)(hw_blk + (l >> 2)) * CIN + (l & 3) * 8;
    char* WtB = (char*)Wt;
    char* YtB = (char*)Yt;

    f32x4 acc[2][7];
#pragma unroll
    for (int s = 0; s < 2; ++s)
#pragma unroll
        for (int j = 0; j < 7; ++j) acc[s][j] = (f32x4){0.f, 0.f, 0.f, 0.f};

    for (int k0 = 0; k0 < CIN; k0 += 32) {
        async_copy16(WtB + (w * 32 + 0) * 64, wg + k0);
        async_copy16(WtB + (w * 32 + 16) * 64, wg + k0 + (size_t)16 * CIN);
        {
            const int j0 = 2 * w;
            async_copy16(YtB + j0 * 16 * 64, yg + k0 + (size_t)(j0 * 16) * CIN);
            if (j0 + 1 < 7)
                async_copy16(YtB + (j0 + 1) * 16 * 64, yg + k0 + (size_t)((j0 + 1) * 16) * CIN);
        }
        __syncthreads();

        s16x8 af[2], bf[7];
#pragma unroll
        for (int s = 0; s < 2; ++s)
            af[s] = *(const s16x8*)(WtB + (w * 32 + s * 16 + lo) * 64 + hi * 16);
#pragma unroll
        for (int j = 0; j < 7; ++j)
            bf[j] = *(const s16x8*)(YtB + (j * 16 + lo) * 64 + hi * 16);
#pragma unroll
        for (int s = 0; s < 2; ++s)
#pragma unroll
            for (int j = 0; j < 7; ++j)
                acc[s][j] = __builtin_amdgcn_mfma_f32_16x16x32_bf16(af[s], bf[j], acc[s][j], 0, 0, 0);
        __syncthreads();
    }

    // epilogue: C/D layout col=lane&15 (hw), row=(lane>>4)*4+reg (o)
#pragma unroll
    for (int s = 0; s < 2; ++s) {
#pragma unroll
        for (int r = 0; r < 4; ++r) {
            const int o = o_blk + w * 32 + s * 16 + hi * 4 + r;
            const float2 ss = scsh[o];
            float m = 0.f;
            float* op = out + (size_t)(n * COUT + o) * HW + hwt * 112 + lo;
#pragma unroll
            for (int j = 0; j < 7; ++j) {
                const float v = fmaxf(fmaf(acc[s][j][r], ss.x, ss.y), 0.f);
                op[j * 16] = v;
                m = fmaxf(m, v);
            }
            m = fmaxf(m, __shfl_xor(m, 1));
            m = fmaxf(m, __shfl_xor(m, 2));
            m = fmaxf(m, __shfl_xor(m, 4));
            m = fmaxf(m, __shfl_xor(m, 8));
            if (lo == 0) atomicMax(&omax[n * COUT + o], __float_as_uint(m));
        }
    }
}

// ---------------- pw channel cut fixup ----------------
__global__ __launch_bounds__(256) void pwcut_kernel(const u32* __restrict__ omax, float* __restrict__ out)
{
    const int b = blockIdx.x;   // n*COUT + o
    if (__uint_as_float(omax[b]) >= PW_TH) return;
    float* p = out + (size_t)b * HW;
    for (int i = threadIdx.x; i < HW; i += 256) p[i] = 0.0f;
}

extern "C" void kernel_launch(void* const* d_in, const int* in_sizes, int n_in,
                              void* d_out, int out_size, void* d_ws, size_t ws_size,
                              hipStream_t stream) {
    const float* x   = (const float*)d_in[0];
    const float* dww = (const float*)d_in[1];
    const float* dwb = (const float*)d_in[2];
    const float* g1  = (const float*)d_in[3];
    const float* b1  = (const float*)d_in[4];
    const float* m1  = (const float*)d_in[5];
    const float* v1  = (const float*)d_in[6];
    const float* pww = (const float*)d_in[7];
    const float* pwb = (const float*)d_in[8];
    const float* g2  = (const float*)d_in[9];
    const float* b2  = (const float*)d_in[10];
    const float* m2  = (const float*)d_in[11];
    const float* v2  = (const float*)d_in[12];
    float* out = (float*)d_out;

    // ws layout: [0,64K) pw omax; [64K,96K) dw max; [96K,100K) scsh; [128K,384K) W bf16; [1M,...) y NHWC bf16
    u32*    omax  = (u32*)d_ws;
    u32*    dwmax = (u32*)((char*)d_ws + (64 << 10));
    float2* scsh  = (float2*)((char*)d_ws + (96 << 10));
    u16*    wbf   = (u16*)((char*)d_ws + (128 << 10));
    u16*    y     = (u16*)((char*)d_ws + (1 << 20));

    prep_kernel<<<64, 256, 0, stream>>>(pww, pwb, g2, b2, m2, v2, wbf, scsh, omax, dwmax);
    dw_kernel<<<NBATCH * 8 * 8, 256, 0, stream>>>(x, dww, dwb, g1, b1, m1, v1, y, dwmax);
    dwcut_kernel<<<NBATCH * CIN, 64, 0, stream>>>(dwmax, y);
    dim3 gpw(HW / 112, COUT / 128, NBATCH);   // 28, 4, 32
    pw_kernel<<<gpw, 256, 0, stream>>>(y, wbf, scsh, out, omax);
    pwcut_kernel<<<NBATCH * COUT, 256, 0, stream>>>(omax, out);
}